// Round 13
// baseline (41.083 us; speedup 1.0000x reference)
//
#include <hip/hip_runtime.h>
#include <math.h>

#define DIM    512
#define REDUC  64
#define T_FULL 4096
#define NB     32
#define SR     10
#define N_SAMP 408     // t = 0,10,...,4070
#define N_LOC  20
#define N_ROWS 428     // per batch: 408 sampled + 20 local
#define EPS    1e-5f

#define RPB   16       // rows per block (1 M-tile)
#define BPB   27       // blocks per batch (block 26: 12 local rows + 4 pad)
#define NPART 26       // blocks 0..25 contain sampled rows

typedef short bf16x8 __attribute__((ext_vector_type(8)));   // 8 bf16 in 4 VGPRs
typedef float f32x4  __attribute__((ext_vector_type(4)));

union Frag { bf16x8 v; uint4 u; };

__device__ __forceinline__ unsigned bf16_rne(float f) {     // round-nearest-even
    unsigned u = __float_as_uint(f);
    return (u + 0x7fffu + ((u >> 16) & 1u)) >> 16;
}
__device__ __forceinline__ unsigned pack2(float lo, float hi) {
    return bf16_rne(lo) | (bf16_rne(hi) << 16);
}

// k0: pre-pack W1 (f32 [512][64]) into bf16 B-fragment order:
// w1p[sg][tile][lane] (16B): lane l holds W1[32sg + 8(l>>4) + f][16tile + (l&15)]
__global__ __launch_bounds__(256) void k0_pack(const float* __restrict__ W1,
                                               uint4* __restrict__ w1p) {
    const int sg = blockIdx.x;                 // K-step 0..15
    const int t  = threadIdx.x;
    const int tile = t >> 6, l = t & 63;
    const int k0 = 32 * sg + 8 * (l >> 4);
    const int j  = 16 * tile + (l & 15);
    float v[8];
#pragma unroll
    for (int f = 0; f < 8; ++f) v[f] = W1[(size_t)(k0 + f) * REDUC + j];
    uint4 o;
    o.x = pack2(v[0], v[1]); o.y = pack2(v[2], v[3]);
    o.z = pack2(v[4], v[5]); o.w = pack2(v[6], v[7]);
    w1p[sg * 256 + t] = o;
}

// k1: comp = LN(relu(x @ W1 + b1)) via bf16 MFMA 16x16x32.
// 16 rows/block, 864 blocks (~3.4/CU co-resident; LDS 21.4 KB). Wave w owns
// col-tile w (16 cols). All 8 x dwordx4 loads issued up front; one barrier;
// 16 MFMAs/wave reading shared A-frags (LDS) + W1 B-frags (w1p, L2-hot).
__global__ __launch_bounds__(256) void k1_rows(
        const float* __restrict__ obs, const uint4* __restrict__ w1p,
        const float* __restrict__ b1, const float* __restrict__ g1,
        const float* __restrict__ beta1,
        float* __restrict__ partials, float* __restrict__ present)
{
    __shared__ Frag  abuf[8][128];         // 16 KB: 16x512 x-tile as bf16 frags
    __shared__ float comp[RPB][66];        // 4.2 KB C tile (+2 pad)
    __shared__ float pmax[4][REDUC];       // 1 KB

    const int t   = threadIdx.x;
    const int l   = t & 63;
    const int w   = __builtin_amdgcn_readfirstlane((int)(t >> 6));
    const int blk = blockIdx.x;
    const int b   = blockIdx.y;

    // staging: thread t = (s2s, cs, l); stages slot (s2s*64+l) of chunks
    // {cs, cs+2, cs+4, cs+6}; slot covers row (l&15), k = 64c+32*s2s+8*(l>>4)+f
    const int s2s = t >> 7;
    const int cs  = (t >> 6) & 1;
    const int rloc = l & 15;
    int rr = blk * RPB + rloc;
    int rc = (rr < N_ROWS) ? rr : 0;       // clamp pad rows (discarded later)
    int tt = (rc < N_SAMP) ? rc * SR : (T_FULL - N_LOC) + (rc - N_SAMP);
    const float* xptr = obs + ((size_t)b * T_FULL + tt) * DIM
                        + 32 * s2s + 8 * (l >> 4);

    float4 xa[4], xb[4];
#pragma unroll
    for (int i = 0; i < 4; ++i) {
        const int c = 2 * i + cs;
        xa[i] = *(const float4*)(xptr + 64 * c);
        xb[i] = *(const float4*)(xptr + 64 * c + 4);
    }
#pragma unroll
    for (int i = 0; i < 4; ++i) {
        Frag fr;
        fr.u.x = pack2(xa[i].x, xa[i].y); fr.u.y = pack2(xa[i].z, xa[i].w);
        fr.u.z = pack2(xb[i].x, xb[i].y); fr.u.w = pack2(xb[i].z, xb[i].w);
        abuf[2 * i + cs][s2s * 64 + l] = fr;
    }
    __syncthreads();

    // MFMA: wave w = col-tile w (cols 16w..16w+15)
    f32x4 acc = {0.f, 0.f, 0.f, 0.f};
#pragma unroll
    for (int c = 0; c < 8; ++c) {
#pragma unroll
        for (int s2 = 0; s2 < 2; ++s2) {
            const int sg = 2 * c + s2;
            Frag A; A.u = abuf[c][s2 * 64 + l].u;
            Frag B; B.u = w1p[(sg * 4 + w) * 64 + l];
            acc = __builtin_amdgcn_mfma_f32_16x16x32_bf16(A.v, B.v, acc, 0, 0, 0);
        }
    }
    // write C: D[m=(l>>4)*4+r][n=l&15]
#pragma unroll
    for (int r = 0; r < 4; ++r)
        comp[4 * (l >> 4) + r][16 * w + (l & 15)] = acc[r];
    __syncthreads();

    // LN epilogue: wave w owns rows 4w..4w+3; lane l = output dim j
    const float g1v = g1[l], be1v = beta1[l], b1v = b1[l];
    float wmax = -INFINITY;
#pragma unroll
    for (int r8 = 0; r8 < 4; ++r8) {
        int rl  = 4 * w + r8;
        int rr2 = blk * RPB + rl;
        float y = fmaxf(comp[rl][l] + b1v, 0.f);
        float s = y;
#pragma unroll
        for (int off = 32; off >= 1; off >>= 1) s += __shfl_xor(s, off);
        float mu = s * (1.f / 64.f);
        float d  = y - mu;
        float v  = d * d;
#pragma unroll
        for (int off = 32; off >= 1; off >>= 1) v += __shfl_xor(v, off);
        float cres = d * rsqrtf(v * (1.f / 64.f) + EPS) * g1v + be1v;

        if (rr2 < N_SAMP) {
            wmax = fmaxf(wmax, cres);
        } else if (rr2 < N_ROWS) {
            present[((size_t)b * N_LOC + (rr2 - N_SAMP)) * REDUC + l] = cres;
        }
    }

    pmax[w][l] = wmax;
    __syncthreads();
    if (w == 0 && blk < NPART) {
        float m = fmaxf(fmaxf(pmax[0][l], pmax[1][l]),
                        fmaxf(pmax[2][l], pmax[3][l]));
        partials[((size_t)b * NPART + blk) * REDUC + l] = m;
    }
}

// k2: one block per batch (32 blocks x 256 thr); g = max(partials,
// cummax(present)); out = LN(relu(g @ W2 + b2)) in f32. W2 read once per
// block -> 4 MB L2 total (vs 80 MB in the 640-block version).
__global__ __launch_bounds__(256) void k2_out(
        const float* __restrict__ partials,
        const float* __restrict__ present,
        const float* __restrict__ W2, const float* __restrict__ b2,
        const float* __restrict__ g2, const float* __restrict__ beta2,
        float* __restrict__ out)
{
    __shared__ float gall[N_LOC][REDUC];   // cummax'd g rows
    __shared__ float red[N_LOC][4];
    __shared__ float redv[N_LOC][4];

    const int b = blockIdx.x;
    const int t = threadIdx.x;
    const int l = t & 63;
    const int wv = t >> 6;

    if (t < REDUC) {
        float m = -INFINITY;
#pragma unroll
        for (int p = 0; p < NPART; ++p)
            m = fmaxf(m, partials[((size_t)b * NPART + p) * REDUC + t]);
        for (int s = 0; s < N_LOC; ++s) {
            m = fmaxf(m, present[((size_t)b * N_LOC + s) * REDUC + t]);
            gall[s][t] = m;
        }
    }
    __syncthreads();

    // GEMV: thread t owns cols j0 = t, j1 = t + 256; f32 throughout
    const int j0 = t, j1 = t + 256;
    float acc0[N_LOC], acc1[N_LOC];
    {
        const float b20 = b2[j0], b21 = b2[j1];
#pragma unroll
        for (int r = 0; r < N_LOC; ++r) { acc0[r] = b20; acc1[r] = b21; }
    }
    for (int k = 0; k < REDUC; ++k) {
        float w0  = W2[(size_t)k * DIM + j0];
        float w1v = W2[(size_t)k * DIM + j1];
#pragma unroll
        for (int r = 0; r < N_LOC; ++r) {
            float gv = gall[r][k];
            acc0[r] = fmaf(gv, w0,  acc0[r]);
            acc1[r] = fmaf(gv, w1v, acc1[r]);
        }
    }

    // relu + row-LN over 512 (20 rows concurrently; 4-wave block reduce)
#pragma unroll
    for (int r = 0; r < N_LOC; ++r) {
        acc0[r] = fmaxf(acc0[r], 0.f);
        acc1[r] = fmaxf(acc1[r], 0.f);
        float s = acc0[r] + acc1[r];
#pragma unroll
        for (int off = 32; off >= 1; off >>= 1) s += __shfl_xor(s, off);
        if (l == 0) red[r][wv] = s;
    }
    __syncthreads();
    float mu[N_LOC];
#pragma unroll
    for (int r = 0; r < N_LOC; ++r)
        mu[r] = (red[r][0] + red[r][1] + red[r][2] + red[r][3]) * (1.f / 512.f);
#pragma unroll
    for (int r = 0; r < N_LOC; ++r) {
        float d0 = acc0[r] - mu[r], d1 = acc1[r] - mu[r];
        float v = d0 * d0 + d1 * d1;
#pragma unroll
        for (int off = 32; off >= 1; off >>= 1) v += __shfl_xor(v, off);
        if (l == 0) redv[r][wv] = v;
    }
    __syncthreads();
    {
        const float g20 = g2[j0], g21 = g2[j1];
        const float be20 = beta2[j0], be21 = beta2[j1];
#pragma unroll
        for (int r = 0; r < N_LOC; ++r) {
            float var = (redv[r][0] + redv[r][1] + redv[r][2] + redv[r][3]) * (1.f / 512.f);
            float inv = rsqrtf(var + EPS);
            out[((size_t)b * N_LOC + r) * DIM + j0] = (acc0[r] - mu[r]) * inv * g20 + be20;
            out[((size_t)b * N_LOC + r) * DIM + j1] = (acc1[r] - mu[r]) * inv * g21 + be21;
        }
    }
}

extern "C" void kernel_launch(void* const* d_in, const int* in_sizes, int n_in,
                              void* d_out, int out_size, void* d_ws, size_t ws_size,
                              hipStream_t stream) {
    const float* obs   = (const float*)d_in[0];
    const float* W1    = (const float*)d_in[1];
    const float* b1    = (const float*)d_in[2];
    const float* g1    = (const float*)d_in[3];
    const float* beta1 = (const float*)d_in[4];
    const float* W2    = (const float*)d_in[5];
    const float* b2    = (const float*)d_in[6];
    const float* g2    = (const float*)d_in[7];
    const float* beta2 = (const float*)d_in[8];
    float* out = (float*)d_out;

    // ws: w1p (64KB) | partials [32][26][64] f32 | present [32][20][64] f32
    uint4* w1p      = (uint4*)d_ws;
    float* partials = (float*)((char*)d_ws + 65536);
    float* present  = partials + (size_t)NB * NPART * REDUC;

    k0_pack<<<16, 256, 0, stream>>>(W1, w1p);
    dim3 g1d(BPB, NB);
    k1_rows<<<g1d, 256, 0, stream>>>(obs, w1p, b1, g1, beta1, partials, present);
    k2_out<<<NB, 256, 0, stream>>>(partials, present, W2, b2, g2, beta2, out);
}